// Round 9
// baseline (154.896 us; speedup 1.0000x reference)
//
#include <hip/hip_runtime.h>
#include <hip/hip_bf16.h>
#include <cfloat>

// B=32, N=2048 -> BN=65536 rows, D=128, K=1024 codes
#define DIM 128
#define NCODES 1024
#define MTILE 128            // rows per block = 4 waves x 32 rows
#define ROWS_PER_WAVE 32
#define NSUB 2               // 16-row M-subtiles per wave
#define KSTEPS 4             // K=128 / 32
#define NKB 2                // K-split: blocks per row-tile
#define CODES_PER_STEP 32
#define NSTEPS_TOTAL (NCODES / CODES_PER_STEP)   // 32
#define NSTEPS_BLK (NSTEPS_TOTAL / NKB)          // 16 per block
#define KB_CODES (NCODES / NKB)                  // 512
#define PART_HALVES 4096     // hi (or lo) halves per 32-code step block
#define STEP_HALVES 8192     // hi+lo per step = 16 KB
#define LOSS_SCALE (12.5f / 8388608.0f)

typedef _Float16 f16x8 __attribute__((ext_vector_type(8)));
typedef float f32x4 __attribute__((ext_vector_type(4)));
typedef unsigned long long u64;

// prep: E (fp32) -> f16 hi/lo split in MFMA-fragment chunk order (r8 layout:
// staging copies and ds_read_b128 fragment reads both lane-consecutive,
// conflict-free); enorm = ||E_k||^2; block 0 zeroes loss.
__global__ __launch_bounds__(128) void prep_kernel(const float* __restrict__ E,
                                                   _Float16* __restrict__ Es,
                                                   float* __restrict__ enorm,
                                                   float* __restrict__ loss) {
    const int code = blockIdx.x;
    const int d = threadIdx.x;
    if (code == 0 && d == 0) *loss = 0.f;
    float e = E[code * DIM + d];
    _Float16 h = (_Float16)e;
    _Float16 l = (_Float16)(e - (float)h);
    const int st = code >> 5, u = (code >> 4) & 1, m16 = code & 15;
    const int ks = d >> 5, quad = (d >> 3) & 3, j = d & 7;
    const int chunk = ks * 128 + u * 64 + quad * 16 + m16;
    const size_t base = (size_t)st * STEP_HALVES + (size_t)chunk * 8 + j;
    Es[base] = h;
    Es[base + PART_HALVES] = l;
    float sq = e * e;
#pragma unroll
    for (int off = 32; off > 0; off >>= 1) sq += __shfl_down(sq, off, 64);
    __shared__ float s2[2];
    if ((d & 63) == 0) s2[d >> 6] = sq;
    __syncthreads();
    if (d == 0) enorm[code] = s2[0] + s2[1];
}

__device__ __forceinline__ unsigned ord_f32(float f) {
    unsigned u = __float_as_uint(f);
    return (u & 0x80000000u) ? ~u : (u | 0x80000000u);
}

// MFMA dist + argmin over a K-half, K-split across blocks for 4 blocks/CU.
// r8 post-mortem: grid 512 = 2 blocks/CU, no pipe >40% busy -> per-step serial
// chain latency-bound. This round: grid 1024 (x2 K-split), 16 waves/CU, 4
// independent barrier domains. Cross-block merge: packed atomicMin
// (ordered-dist<<32 | index) -- dist bits deterministic per (row,code), so
// min == lexicographic == jnp first-index rule. Loss = sum(znorm) [added here
// by khalf==0 blocks] + sum(best dist') [added by finish kernel].
// r3 lesson: no runtime-indexed register arrays. r5: stay on (256,2).
__global__ __launch_bounds__(256, 2) void vq_kernel(const float* __restrict__ z,
                                                    const _Float16* __restrict__ Es,
                                                    const float* __restrict__ enorm,
                                                    u64* __restrict__ winners,
                                                    float* __restrict__ loss) {
    const int t = threadIdx.x;
    const int lane = t & 63;
    const int wave = t >> 6;     // row-wave: rows [wave*32, wave*32+32)
    const int m16 = lane & 15;   // A row within subtile / B,C code col
    const int quad = lane >> 4;  // k-group for A/B; row-group for C
    const int rowtile = blockIdx.x >> 1;  // twins adjacent -> z reads L2-shared
    const int khalf = blockIdx.x & 1;

    __shared__ _Float16 s_b[2][STEP_HALVES];  // 2 x 16 KB double buffer
    __shared__ float s_enorm[KB_CODES];       // this half's 512 norms, 2 KB
    __shared__ float s_znorm[MTILE];          // 0.5 KB

    for (int i = t; i < KB_CODES; i += 256) s_enorm[i] = enorm[khalf * KB_CODES + i];

    // ---- A fragments: wave's 32 rows, K=128, scaled by -2, f16 hi/lo split.
    // A layout (16x16x32): lane holds A[m=lane&15][k=quad*8+j], j=0..7.
    f16x8 Ahi[NSUB][KSTEPS], Alo[NSUB][KSTEPS];
    float znp[NSUB] = {0.f, 0.f};
    const int rowbase = rowtile * MTILE + wave * ROWS_PER_WAVE;
#pragma unroll
    for (int s = 0; s < NSUB; ++s) {
        const int row = rowbase + s * 16 + m16;
        const float* zp = z + (size_t)row * DIM + quad * 8;
#pragma unroll
        for (int ks = 0; ks < KSTEPS; ++ks) {
            float4 v0 = *(const float4*)(zp + ks * 32);
            float4 v1 = *(const float4*)(zp + ks * 32 + 4);
            float zv[8] = {v0.x, v0.y, v0.z, v0.w, v1.x, v1.y, v1.z, v1.w};
#pragma unroll
            for (int j = 0; j < 8; ++j) {
                znp[s] = fmaf(zv[j], zv[j], znp[s]);
                float tt = -2.f * zv[j];
                _Float16 h = (_Float16)tt;
                Ahi[s][ks][j] = h;
                Alo[s][ks][j] = (_Float16)(tt - (float)h);
            }
        }
    }
#pragma unroll
    for (int s = 0; s < NSUB; ++s) {
        float v = znp[s];
        v += __shfl_xor(v, 16, 64);
        v += __shfl_xor(v, 32, 64);
        if (quad == 0) s_znorm[wave * ROWS_PER_WAVE + s * 16 + m16] = v;
    }

    float bestv[NSUB][4];
    int besti[NSUB][4];
#pragma unroll
    for (int s = 0; s < NSUB; ++s)
#pragma unroll
        for (int r = 0; r < 4; ++r) {
            bestv[s][r] = FLT_MAX;
            besti[s][r] = 0;
        }

    // Stage step's 16 KB tile: 1024 16B chunks; global contiguous, LDS
    // lane-consecutive (conflict-free).
#define STAGE(STG, B)                                                \
    {                                                                \
        const _Float16* src = Es + (size_t)(STG)*STEP_HALVES;        \
        _Pragma("unroll") for (int c = 0; c < 4; ++c) {              \
            const int idx = t + c * 256;                             \
            *(f16x8*)&s_b[B][(size_t)idx * 8] =                      \
                *(const f16x8*)(src + (size_t)idx * 8);              \
        }                                                            \
    }

    const int stg0 = khalf * NSTEPS_BLK;
    STAGE(stg0, 0)
    __syncthreads();

    // khalf==0 blocks contribute sum(znorm) to the loss (wave 0 only; no
    // extra barrier -- ordering provided by the staging barrier above).
    if (khalf == 0 && wave == 0) {
        float lp = s_znorm[lane] + s_znorm[lane + 64];
#pragma unroll
        for (int off = 32; off > 0; off >>= 1) lp += __shfl_down(lp, off, 64);
        if (lane == 0) atomicAdd(loss, lp * LOSS_SCALE);
    }

    int buf = 0;
    for (int st = 0; st < NSTEPS_BLK; ++st) {
        if (st + 1 < NSTEPS_BLK) STAGE(stg0 + st + 1, buf ^ 1)
        const _Float16* bh = s_b[buf];
        const _Float16* bl = s_b[buf] + PART_HALVES;
#pragma unroll
        for (int u = 0; u < 2; ++u) {  // two 16-code subgroups
            f16x8 Bh[KSTEPS], Bl[KSTEPS];
#pragma unroll
            for (int ks = 0; ks < KSTEPS; ++ks) {
                const int chunk = ks * 128 + u * 64 + lane;  // lane-consecutive
                Bh[ks] = *(const f16x8*)(bh + (size_t)chunk * 8);
                Bl[ks] = *(const f16x8*)(bl + (size_t)chunk * 8);
            }
            f32x4 acc_hh[NSUB], acc_c[NSUB];
#pragma unroll
            for (int s = 0; s < NSUB; ++s) {
                acc_hh[s] = (f32x4){0.f, 0.f, 0.f, 0.f};
                acc_c[s] = (f32x4){0.f, 0.f, 0.f, 0.f};
            }
#pragma unroll
            for (int ks = 0; ks < KSTEPS; ++ks)
#pragma unroll
                for (int s = 0; s < NSUB; ++s) {
                    acc_c[s] = __builtin_amdgcn_mfma_f32_16x16x32_f16(Ahi[s][ks], Bl[ks], acc_c[s], 0, 0, 0);
                    acc_c[s] = __builtin_amdgcn_mfma_f32_16x16x32_f16(Alo[s][ks], Bh[ks], acc_c[s], 0, 0, 0);
                    acc_hh[s] = __builtin_amdgcn_mfma_f32_16x16x32_f16(Ahi[s][ks], Bh[ks], acc_hh[s], 0, 0, 0);
                }
            const int nloc = st * CODES_PER_STEP + u * 16 + m16;
            const float e = s_enorm[nloc];
            const int n = khalf * KB_CODES + nloc;  // global code index
            // C layout: col = lane&15 (code), row = quad*4 + r
#pragma unroll
            for (int s = 0; s < NSUB; ++s)
#pragma unroll
                for (int r = 0; r < 4; ++r) {
                    float d = (acc_hh[s][r] + acc_c[s][r]) + e;
                    if (d < bestv[s][r]) {  // strict <, ascending n => first-index
                        bestv[s][r] = d;
                        besti[s][r] = n;
                    }
                }
        }
        __syncthreads();
        buf ^= 1;
    }
#undef STAGE

    // ---- in-wave argmin across the 16 m16-lanes (lexicographic (v,i))
#pragma unroll
    for (int s = 0; s < NSUB; ++s)
#pragma unroll
        for (int r = 0; r < 4; ++r) {
            float v = bestv[s][r];
            int i = besti[s][r];
#pragma unroll
            for (int m = 1; m <= 8; m <<= 1) {
                float ov = __shfl_xor(v, m, 64);
                int oi = __shfl_xor(i, m, 64);
                if (ov < v || (ov == v && oi < i)) {
                    v = ov;
                    i = oi;
                }
            }
            bestv[s][r] = v;
            besti[s][r] = i;
        }

    // ---- cross-block merge: packed device-scope atomicMin per row.
    // key = ordered(dist)<<32 | index; dist bits deterministic per (row,code)
    // across blocks => min key == (min dist, then min index).
    if (m16 == 0) {
#pragma unroll
        for (int s = 0; s < NSUB; ++s)
#pragma unroll
            for (int r = 0; r < 4; ++r) {
                const int row = rowbase + s * 16 + quad * 4 + r;
                u64 key = ((u64)ord_f32(bestv[s][r]) << 32) | (unsigned)besti[s][r];
                atomicMin(&winners[row], key);
            }
    }
}

// finish: decode winners -> gather z_q + loss(dist part).
// 64 rows per 256-thread block.
__global__ __launch_bounds__(256) void finish_kernel(const u64* __restrict__ winners,
                                                     const float* __restrict__ E,
                                                     float* __restrict__ out,
                                                     float* __restrict__ loss) {
    const int t = threadIdx.x;
    __shared__ int s_ind[64];
    const int row0 = blockIdx.x * 64;
    float lp = 0.f;
    if (t < 64) {
        u64 w = winners[row0 + t];
        s_ind[t] = (int)(unsigned)w;
        unsigned ou = (unsigned)(w >> 32);
        unsigned bits = (ou & 0x80000000u) ? (ou ^ 0x80000000u) : ~ou;
        lp = __uint_as_float(bits);  // best dist' = ||E||^2 - 2 z.E
#pragma unroll
        for (int off = 32; off > 0; off >>= 1) lp += __shfl_down(lp, off, 64);
        if (t == 0) atomicAdd(loss, lp * LOSS_SCALE);
    }
    __syncthreads();
    const float4* E4 = (const float4*)E;
    float4* out4 = (float4*)(out + (size_t)row0 * DIM);
#pragma unroll
    for (int i = 0; i < (64 * DIM) / (256 * 4); ++i) {  // 8
        const int f = t + i * 256;
        const int r = f >> 5;  // 32 float4 per row
        const int d = f & 31;
        out4[f] = E4[(size_t)s_ind[r] * 32 + d];
    }
}

extern "C" void kernel_launch(void* const* d_in, const int* in_sizes, int n_in,
                              void* d_out, int out_size, void* d_ws, size_t ws_size,
                              hipStream_t stream) {
    const float* z = (const float*)d_in[0];  // [BN,128] fp32
    const float* E = (const float*)d_in[1];  // [1024,128] fp32
    float* out = (float*)d_out;              // [BN*128] z_q + [1] loss
    float* loss = out + (size_t)(out_size - 1);
    _Float16* Es = (_Float16*)d_ws;                              // 512 KB
    float* enorm = (float*)(Es + (size_t)NCODES * DIM * 2);      // 4 KB
    u64* winners = (u64*)(enorm + NCODES);                       // 512 KB
    const int BN = in_sizes[0] / DIM;

    prep_kernel<<<NCODES, 128, 0, stream>>>(E, Es, enorm, loss);
    hipMemsetAsync(winners, 0xFF, (size_t)BN * sizeof(u64), stream);
    vq_kernel<<<(BN / MTILE) * NKB, 256, 0, stream>>>(z, Es, enorm, winners, loss);
    finish_kernel<<<BN / 64, 256, 0, stream>>>(winners, E, out, loss);
}